// Round 1
// baseline (102.669 us; speedup 1.0000x reference)
//
#include <hip/hip_runtime.h>

// QCNN collapses to: apply 23 two-qubit gates to the 13-qubit pure state,
// then P(bit0 == 0) / ||psi0||^2.  One block per batch element, psi in LDS.

#define NT 512          // threads per block (8 waves)
#define DIM 8192        // 2^13 amplitudes

__device__ __forceinline__ float2 cadd(float2 a, float2 b) {
    return make_float2(a.x + b.x, a.y + b.y);
}
__device__ __forceinline__ float2 cmul(float2 a, float2 b) {
    return make_float2(a.x * b.x - a.y * b.y, a.x * b.y + a.y * b.x);
}
__device__ __forceinline__ float2 cmac(float2 acc, float2 a, float2 b) {
    acc.x = fmaf(a.x, b.x, fmaf(-a.y, b.y, acc.x));
    acc.y = fmaf(a.x, b.y, fmaf(a.y, b.x, acc.y));
    return acc;
}
__device__ __forceinline__ float2 shflc(float2 v, int src) {
    return make_float2(__shfl(v.x, src, 64), __shfl(v.y, src, 64));
}

// Each wave computes all four U_l = expm(H_l - H_l^dagger) redundantly.
// Lane l holds entry (r,c) = ((l>>2)&3, l&3) of matrix m = l>>4.
// Scaling-and-squaring with Taylor K=10; 4x4 complex matmul via shfl.
__device__ float2 expm_entry(const float* __restrict__ Hr,
                             const float* __restrict__ Hi) {
    const int lane = threadIdx.x & 63;
    const int m = lane >> 4, e = lane & 15, r = e >> 2, c = e & 3;
    const int base = lane & 48;

    // A = H - H^dagger  (anti-hermitian)
    float are = Hr[m * 16 + r * 4 + c] - Hr[m * 16 + c * 4 + r];
    float aim = Hi[m * 16 + r * 4 + c] + Hi[m * 16 + c * 4 + r];

    // inf-norm upper bound: max_r sum_c (|re|+|im|); make it wave-uniform
    float v = fabsf(are) + fabsf(aim);
    v += __shfl_xor(v, 1, 64);
    v += __shfl_xor(v, 2, 64);
    v = fmaxf(v, __shfl_xor(v, 4, 64));
    v = fmaxf(v, __shfl_xor(v, 8, 64));
    v = fmaxf(v, __shfl_xor(v, 16, 64));
    v = fmaxf(v, __shfl_xor(v, 32, 64));

    int s = 0;
    while (v > 0.25f && s < 30) { v *= 0.5f; s++; }   // wave-uniform loop
    const float scale = ldexpf(1.0f, -s);

    float2 X = make_float2(are * scale, aim * scale);
    float2 E = X;
    if (r == c) E.x += 1.0f;        // E = I + X
    float2 T = X;

    // Taylor: E = sum_{k=0..10} X^k / k!
    for (int k = 2; k <= 10; k++) {
        float2 acc = make_float2(0.f, 0.f);
        #pragma unroll
        for (int kk = 0; kk < 4; kk++) {
            float2 t = shflc(T, base + r * 4 + kk);
            float2 x = shflc(X, base + kk * 4 + c);
            acc = cmac(acc, t, x);
        }
        const float inv = 1.0f / (float)k;
        T = make_float2(acc.x * inv, acc.y * inv);
        E = cadd(E, T);
    }
    // Square s times: E = E @ E
    for (int i = 0; i < s; i++) {
        float2 acc = make_float2(0.f, 0.f);
        #pragma unroll
        for (int kk = 0; kk < 4; kk++) {
            float2 a = shflc(E, base + r * 4 + kk);
            float2 b = shflc(E, base + kk * 4 + c);
            acc = cmac(acc, a, b);
        }
        E = acc;
    }
    return E;
}

// Gate list: {layer, pa, pb} where pa/pb are BIT POSITIONS in the flat index
// (qubit q <-> bit 12-q).  Row index into U is j = 2*bit(pa) + bit(pb).
// Derived from _conv_pairs + pool relabeling:
//  L0 on 13 qubits; L1 kept = orig {1,3,5,7,9,11,12}; L2 kept = {3,7,11,12};
//  L3 kept = {7,12}; final kept qubit = 12 (bit 0).
__constant__ signed char GL[23][3] = {
    {0, 12, 11}, {0, 10, 9}, {0, 8, 7}, {0, 6, 5}, {0, 4, 3}, {0, 2, 1},
    {0, 11, 10}, {0, 9, 8}, {0, 7, 6}, {0, 5, 4}, {0, 3, 2}, {0, 1, 0},
    {1, 11, 9}, {1, 7, 5}, {1, 3, 1},
    {1, 9, 7}, {1, 5, 3}, {1, 1, 0},
    {2, 9, 5}, {2, 1, 0},
    {2, 5, 1}, {2, 0, 9},
    {3, 5, 0}};

__global__ __launch_bounds__(NT) void qcnn_kernel(
    const float* __restrict__ pr, const float* __restrict__ pi,
    const float* __restrict__ Hr, const float* __restrict__ Hi,
    float* __restrict__ out) {
    __shared__ float2 psi[DIM];   // exactly 64 KiB
    const int tid = threadIdx.x;
    const int b = blockIdx.x;

    // Phase 1: gate unitaries (every wave redundantly; result stays in regs)
    float2 E = expm_entry(Hr, Hi);

    // Phase 2: load psi into LDS; accumulate ||psi||^2 partial in a register
    float norm2p = 0.f;
    const float* prb = pr + b * DIM;
    const float* pib = pi + b * DIM;
    for (int i = tid; i < DIM; i += NT) {
        float re = prb[i], im = pib[i];
        psi[i] = make_float2(re, im);
        norm2p = fmaf(re, re, fmaf(im, im, norm2p));
    }
    __syncthreads();

    // Phase 3: 23 two-qubit gates, one LDS pass each
    int curLayer = -1;
    float2 u[16];
    #pragma unroll 1
    for (int gi = 0; gi < 23; gi++) {
        const int L = GL[gi][0], pa = GL[gi][1], pb = GL[gi][2];
        if (L != curLayer) {  // broadcast U_L entries from this wave's expm lanes
            #pragma unroll
            for (int e = 0; e < 16; e++) u[e] = shflc(E, (L << 4) | e);
            curLayer = L;
        }
        const int ph = pa > pb ? pa : pb;
        const int pl = pa > pb ? pb : pa;
        const int ma = 1 << pa, mb = 1 << pb;
        for (int g = tid; g < DIM / 4; g += NT) {
            int t = ((g >> pl) << (pl + 1)) | (g & ((1 << pl) - 1));
            int base = ((t >> ph) << (ph + 1)) | (t & ((1 << ph) - 1));
            float2 a0 = psi[base];
            float2 a1 = psi[base | mb];
            float2 a2 = psi[base | ma];
            float2 a3 = psi[base | ma | mb];
            float2 n0 = make_float2(0.f, 0.f), n1 = n0, n2 = n0, n3 = n0;
            n0 = cmac(n0, u[0], a0);  n0 = cmac(n0, u[1], a1);
            n0 = cmac(n0, u[2], a2);  n0 = cmac(n0, u[3], a3);
            n1 = cmac(n1, u[4], a0);  n1 = cmac(n1, u[5], a1);
            n1 = cmac(n1, u[6], a2);  n1 = cmac(n1, u[7], a3);
            n2 = cmac(n2, u[8], a0);  n2 = cmac(n2, u[9], a1);
            n2 = cmac(n2, u[10], a2); n2 = cmac(n2, u[11], a3);
            n3 = cmac(n3, u[12], a0); n3 = cmac(n3, u[13], a1);
            n3 = cmac(n3, u[14], a2); n3 = cmac(n3, u[15], a3);
            psi[base] = n0;
            psi[base | mb] = n1;
            psi[base | ma] = n2;
            psi[base | ma | mb] = n3;
        }
        __syncthreads();
    }

    // Phase 4: out[b] = sum_{i even} |psi[i]|^2 / ||psi0||^2
    float s0 = 0.f;
    for (int i = 2 * tid; i < DIM; i += 2 * NT) {
        float2 a = psi[i];
        s0 = fmaf(a.x, a.x, fmaf(a.y, a.y, s0));
    }
    __syncthreads();
    psi[tid] = make_float2(s0, norm2p);
    __syncthreads();
    for (int step = NT / 2; step > 0; step >>= 1) {
        if (tid < step) {
            float2 a = psi[tid], c = psi[tid + step];
            psi[tid] = make_float2(a.x + c.x, a.y + c.y);
        }
        __syncthreads();
    }
    if (tid == 0) out[b] = psi[0].x / psi[0].y;
}

extern "C" void kernel_launch(void* const* d_in, const int* in_sizes, int n_in,
                              void* d_out, int out_size, void* d_ws, size_t ws_size,
                              hipStream_t stream) {
    const float* pr = (const float*)d_in[0];
    const float* pi = (const float*)d_in[1];
    const float* Hr = (const float*)d_in[2];
    const float* Hi = (const float*)d_in[3];
    float* out = (float*)d_out;
    qcnn_kernel<<<dim3(out_size), dim3(NT), 0, stream>>>(pr, pi, Hr, Hi, out);
}

// Round 2
// 81.499 us; speedup vs baseline: 1.2598x; 1.2598x over previous
//
#include <hip/hip_runtime.h>

// QCNN collapsed to pure-state sim: 23 two-qubit gates on 13 qubits, then
// P(bit0==0)/||psi0||^2.  Register-resident schedule: 8 phases, each thread
// holds 16 amplitudes (4 local bits) in VGPRs, applies 2-4 gates register-only,
// exchanges through XOR-swizzled LDS.  One block per batch element.

#define NT 512          // 8 waves
#define DIM 8192        // 2^13 amplitudes

__device__ __forceinline__ float2 cadd(float2 a, float2 b) {
    return make_float2(a.x + b.x, a.y + b.y);
}
__device__ __forceinline__ float2 cmac(float2 acc, float2 a, float2 b) {
    acc.x = fmaf(a.x, b.x, fmaf(-a.y, b.y, acc.x));
    acc.y = fmaf(a.x, b.y, fmaf(a.y, b.x, acc.y));
    return acc;
}
__device__ __forceinline__ float2 shflc(float2 v, int src) {
    return make_float2(__shfl(v.x, src, 64), __shfl(v.y, src, 64));
}
// packed-friendly complex MAC: acc += u * a, with us = (-u.y, u.x) precomputed
__device__ __forceinline__ float2 cmac2(float2 acc, float2 u, float2 us, float2 a) {
    acc.x = fmaf(a.x, u.x, acc.x);
    acc.y = fmaf(a.x, u.y, acc.y);
    acc.x = fmaf(a.y, us.x, acc.x);
    acc.y = fmaf(a.y, us.y, acc.y);
    return acc;
}

// Each wave computes all four U_l = expm(H_l - H_l^dagger) redundantly.
// Lane l holds entry (r,c) = ((l>>2)&3, l&3) of matrix m = l>>4.
__device__ float2 expm_entry(const float* __restrict__ Hr,
                             const float* __restrict__ Hi) {
    const int lane = threadIdx.x & 63;
    const int m = lane >> 4, e = lane & 15, r = e >> 2, c = e & 3;
    const int base = lane & 48;

    float are = Hr[m * 16 + r * 4 + c] - Hr[m * 16 + c * 4 + r];
    float aim = Hi[m * 16 + r * 4 + c] + Hi[m * 16 + c * 4 + r];

    float v = fabsf(are) + fabsf(aim);
    v += __shfl_xor(v, 1, 64);
    v += __shfl_xor(v, 2, 64);
    v = fmaxf(v, __shfl_xor(v, 4, 64));
    v = fmaxf(v, __shfl_xor(v, 8, 64));
    v = fmaxf(v, __shfl_xor(v, 16, 64));
    v = fmaxf(v, __shfl_xor(v, 32, 64));

    int s = 0;
    while (v > 0.25f && s < 30) { v *= 0.5f; s++; }
    const float scale = ldexpf(1.0f, -s);

    float2 X = make_float2(are * scale, aim * scale);
    float2 E = X;
    if (r == c) E.x += 1.0f;
    float2 T = X;
    for (int k = 2; k <= 10; k++) {
        float2 acc = make_float2(0.f, 0.f);
        #pragma unroll
        for (int kk = 0; kk < 4; kk++) {
            float2 t = shflc(T, base + r * 4 + kk);
            float2 x = shflc(X, base + kk * 4 + c);
            acc = cmac(acc, t, x);
        }
        const float inv = 1.0f / (float)k;
        T = make_float2(acc.x * inv, acc.y * inv);
        E = cadd(E, T);
    }
    for (int i = 0; i < s; i++) {
        float2 acc = make_float2(0.f, 0.f);
        #pragma unroll
        for (int kk = 0; kk < 4; kk++) {
            float2 a = shflc(E, base + r * 4 + kk);
            float2 bb = shflc(E, base + kk * 4 + c);
            acc = cmac(acc, a, bb);
        }
        E = acc;
    }
    return E;
}

__device__ __forceinline__ void loadU(float2 E, int L, float2* u, float2* us) {
    #pragma unroll
    for (int e = 0; e < 16; e++) {
        u[e] = shflc(E, (L << 4) | e);
        us[e] = make_float2(-u[e].y, u[e].x);
    }
}

// LDS XOR-swizzle: breaks the power-of-2 strides of every phase's partition
__device__ __forceinline__ int swz(int e) {
    return e ^ ((e >> 4) & 15) ^ ((e >> 8) & 3);
}

// deposit thread bits into the 9 non-local bit positions (compile-time mask)
template<int MASK>
__device__ __forceinline__ int deposit(int t) {
    int r = 0;
    #pragma unroll
    for (int bpos = 0; bpos < 13; bpos++) {
        if (MASK & (1 << bpos)) { r |= (t & 1) << bpos; t >>= 1; }
    }
    return r;
}

template<int B3, int B2, int B1, int B0>
__device__ __forceinline__ int eaddr(int base, int i) {
    return base | (((i >> 3) & 1) << B3) | (((i >> 2) & 1) << B2)
                | (((i >> 1) & 1) << B1) | ((i & 1) << B0);
}

template<int B3, int B2, int B1, int B0, int MASK>
__device__ __forceinline__ void phase_read(float2* v, const float2* psi, int t) {
    const int base = deposit<MASK>(t);
    #pragma unroll
    for (int i = 0; i < 16; i++) v[i] = psi[swz(eaddr<B3, B2, B1, B0>(base, i))];
}
template<int B3, int B2, int B1, int B0, int MASK>
__device__ __forceinline__ void phase_write(const float2* v, float2* psi, int t) {
    const int base = deposit<MASK>(t);
    #pragma unroll
    for (int i = 0; i < 16; i++) psi[swz(eaddr<B3, B2, B1, B0>(base, i))] = v[i];
}

// apply 4x4 gate U on local index bits (KA, KB); row index = 2*bit(KA)+bit(KB)
template<int KA, int KB>
__device__ __forceinline__ void apply_gate(float2* v, const float2* u, const float2* us) {
    const int MA = 1 << KA, MB = 1 << KB;
    #pragma unroll
    for (int i = 0; i < 16; i++) {
        if (i & (MA | MB)) continue;
        float2 a0 = v[i], a1 = v[i | MB], a2 = v[i | MA], a3 = v[i | MA | MB];
        float2 n0 = make_float2(0.f, 0.f);
        n0 = cmac2(n0, u[0], us[0], a0);  n0 = cmac2(n0, u[1], us[1], a1);
        n0 = cmac2(n0, u[2], us[2], a2);  n0 = cmac2(n0, u[3], us[3], a3);
        float2 n1 = make_float2(0.f, 0.f);
        n1 = cmac2(n1, u[4], us[4], a0);  n1 = cmac2(n1, u[5], us[5], a1);
        n1 = cmac2(n1, u[6], us[6], a2);  n1 = cmac2(n1, u[7], us[7], a3);
        float2 n2 = make_float2(0.f, 0.f);
        n2 = cmac2(n2, u[8], us[8], a0);  n2 = cmac2(n2, u[9], us[9], a1);
        n2 = cmac2(n2, u[10], us[10], a2); n2 = cmac2(n2, u[11], us[11], a3);
        float2 n3 = make_float2(0.f, 0.f);
        n3 = cmac2(n3, u[12], us[12], a0); n3 = cmac2(n3, u[13], us[13], a1);
        n3 = cmac2(n3, u[14], us[14], a2); n3 = cmac2(n3, u[15], us[15], a3);
        v[i] = n0; v[i | MB] = n1; v[i | MA] = n2; v[i | MA | MB] = n3;
    }
}

__global__ __launch_bounds__(NT) void qcnn_kernel(
    const float* __restrict__ pr, const float* __restrict__ pi,
    const float* __restrict__ Hr, const float* __restrict__ Hi,
    float* __restrict__ out) {
    __shared__ float2 psi[DIM];   // 64 KiB
    const int tid = threadIdx.x;
    const int b = blockIdx.x;

    // issue state loads first so they overlap the serial expm chain
    const float* prb = pr + b * DIM;
    const float* pib = pi + b * DIM;
    float re[16], im[16];
    #pragma unroll
    for (int i = 0; i < 16; i++) {
        re[i] = prb[tid | (i << 9)];
        im[i] = pib[tid | (i << 9)];
    }

    float2 E = expm_entry(Hr, Hi);

    float2 v[16];
    float norm2p = 0.f;
    #pragma unroll
    for (int i = 0; i < 16; i++) {
        v[i] = make_float2(re[i], im[i]);
        norm2p = fmaf(re[i], re[i], fmaf(im[i], im[i], norm2p));
    }

    float2 u[16], us[16];
    loadU(E, 0, u, us);

    // P1: local bits (12,11,10,9); loaded directly from global (e = tid | i<<9)
    apply_gate<3, 2>(v, u, us);   // (12,11)
    apply_gate<1, 0>(v, u, us);   // (10,9)
    apply_gate<2, 1>(v, u, us);   // (11,10)
    phase_write<12, 11, 10, 9, 0x01FF>(v, psi, tid);
    __syncthreads();

    // P2: local (8,7,6,5)
    phase_read<8, 7, 6, 5, 0x1E1F>(v, psi, tid);
    apply_gate<3, 2>(v, u, us);   // (8,7)
    apply_gate<1, 0>(v, u, us);   // (6,5)
    apply_gate<2, 1>(v, u, us);   // (7,6)
    phase_write<8, 7, 6, 5, 0x1E1F>(v, psi, tid);
    __syncthreads();

    // P3: local (3,2,1,0)
    phase_read<3, 2, 1, 0, 0x1FF0>(v, psi, tid);
    apply_gate<2, 1>(v, u, us);   // (2,1)
    apply_gate<1, 0>(v, u, us);   // (1,0)
    phase_write<3, 2, 1, 0, 0x1FF0>(v, psi, tid);
    __syncthreads();

    // P4: local (5,4,3,2)
    phase_read<5, 4, 3, 2, 0x1FC3>(v, psi, tid);
    apply_gate<2, 1>(v, u, us);   // (4,3)
    apply_gate<3, 2>(v, u, us);   // (5,4)
    apply_gate<1, 0>(v, u, us);   // (3,2)
    phase_write<5, 4, 3, 2, 0x1FC3>(v, psi, tid);
    __syncthreads();

    // P5: local (11,9,8,7)
    phase_read<11, 9, 8, 7, 0x147F>(v, psi, tid);
    apply_gate<2, 1>(v, u, us);   // (9,8)  layer 0
    loadU(E, 1, u, us);
    apply_gate<3, 2>(v, u, us);   // (11,9) layer 1
    phase_write<11, 9, 8, 7, 0x147F>(v, psi, tid);
    __syncthreads();

    // P6: local (7,5,3,1)
    phase_read<7, 5, 3, 1, 0x1F55>(v, psi, tid);
    apply_gate<3, 2>(v, u, us);   // (7,5)
    apply_gate<1, 0>(v, u, us);   // (3,1)
    apply_gate<2, 1>(v, u, us);   // (5,3)
    phase_write<7, 5, 3, 1, 0x1F55>(v, psi, tid);
    __syncthreads();

    // P7: local (9,7,1,0)
    phase_read<9, 7, 1, 0, 0x1D7C>(v, psi, tid);
    apply_gate<3, 2>(v, u, us);   // (9,7)  layer 1
    apply_gate<1, 0>(v, u, us);   // (1,0)  layer 1
    loadU(E, 2, u, us);
    apply_gate<1, 0>(v, u, us);   // (1,0)  layer 2
    phase_write<9, 7, 1, 0, 0x1D7C>(v, psi, tid);
    __syncthreads();

    // P8: local (9,5,1,0) — final phase, no write-back
    phase_read<9, 5, 1, 0, 0x1DDC>(v, psi, tid);
    apply_gate<3, 2>(v, u, us);   // (9,5)  layer 2
    apply_gate<2, 1>(v, u, us);   // (5,1)  layer 2
    apply_gate<0, 3>(v, u, us);   // (0,9)  layer 2
    loadU(E, 3, u, us);
    apply_gate<2, 0>(v, u, us);   // (5,0)  layer 3

    // local bit0 == element bit0: sum |amp|^2 over even elements
    float s0 = 0.f;
    #pragma unroll
    for (int i = 0; i < 16; i += 2) {
        s0 = fmaf(v[i].x, v[i].x, fmaf(v[i].y, v[i].y, s0));
    }

    // wave reduce, then block reduce via LDS
    #pragma unroll
    for (int off = 1; off < 64; off <<= 1) {
        s0 += __shfl_xor(s0, off, 64);
        norm2p += __shfl_xor(norm2p, off, 64);
    }
    __syncthreads();   // all P8 reads done before psi reuse
    if ((tid & 63) == 0) psi[tid >> 6] = make_float2(s0, norm2p);
    __syncthreads();
    if (tid == 0) {
        float S = 0.f, Nrm = 0.f;
        #pragma unroll
        for (int w = 0; w < NT / 64; w++) { S += psi[w].x; Nrm += psi[w].y; }
        out[b] = S / Nrm;
    }
}

extern "C" void kernel_launch(void* const* d_in, const int* in_sizes, int n_in,
                              void* d_out, int out_size, void* d_ws, size_t ws_size,
                              hipStream_t stream) {
    const float* pr = (const float*)d_in[0];
    const float* pi = (const float*)d_in[1];
    const float* Hr = (const float*)d_in[2];
    const float* Hi = (const float*)d_in[3];
    float* out = (float*)d_out;
    qcnn_kernel<<<dim3(out_size), dim3(NT), 0, stream>>>(pr, pi, Hr, Hi, out);
}